// Round 13
// baseline (565.621 us; speedup 1.0000x reference)
//
#include <hip/hip_runtime.h>

typedef __bf16 bf16_t;
typedef bf16_t bf16x8 __attribute__((ext_vector_type(8)));
typedef float f32x16 __attribute__((ext_vector_type(16)));
typedef unsigned short u16x8_t __attribute__((ext_vector_type(8)));
typedef unsigned int u32x4_t __attribute__((ext_vector_type(4)));

#define HD 64
#define TOTTOK 49152

static __device__ __forceinline__ unsigned short f2b(float f) {
    bf16_t h = (bf16_t)f;
    return __builtin_bit_cast(unsigned short, h);
}
static __device__ __forceinline__ bf16x8 asbf(u16x8_t u) { return __builtin_bit_cast(bf16x8, u); }
static __device__ __forceinline__ bf16x8 asbf4(u32x4_t u) { return __builtin_bit_cast(bf16x8, u); }
static __device__ __forceinline__ unsigned int pk2(float lo, float hi) {
    return (unsigned int)f2b(lo) | ((unsigned int)f2b(hi) << 16);
}

__global__ __launch_bounds__(256, 2)
void flash_attn_kernel(const float* __restrict__ Q, const float* __restrict__ K,
                       const float* __restrict__ V, float* __restrict__ O)
{
    // Fragment-major LDS, double-buffered; 8 chunks x 512 shorts each; all
    // frag reads are lane-linear ds_read_b128 (conflict-free, 16B-aligned,
    // immediate chunk offsets).
    // Kf chunk c2 = kt*4+kk : lane holds K[kt*32+(l&31)][kk*16+(l>>5)*8+i]
    // Vf chunk c2 = dt*4+kk4: lane holds V[kk4*16+(l>>5)*8+i][dt*32+(l&31)]
    __shared__ unsigned short Kf[2][4096];
    __shared__ unsigned short Vff[2][4096];

    const int bid = blockIdx.x;
    int Slen, bl2, off, qtl2, base;
    if (bid < 512)       { Slen = 2048; bl2 = 3; off = 32768; qtl2 = 3; base = 0;    }
    else if (bid < 1024) { Slen = 1024; bl2 = 4; off = 16384; qtl2 = 2; base = 512;  }
    else                 { Slen = 512;  bl2 = 5; off = 0;     qtl2 = 1; base = 1024; }
    const int l    = bid - base;
    const int xcd  = l & 7;
    const int slot = l >> 3;
    const int p    = xcd + ((slot >> qtl2) << 3);
    const int qblk = slot & ((1 << qtl2) - 1);
    const int hh   = p >> bl2;
    const int sj   = p & ((1 << bl2) - 1);

    const size_t seqbase = ((size_t)hh * TOTTOK + (size_t)off + (size_t)sj * Slen) * HD;
    const float* Qb = Q + seqbase + (size_t)(qblk * 256) * HD;
    const float* Kb = K + seqbase;
    const float* Vb = V + seqbase;
    float*       Ob = O + seqbase + (size_t)(qblk * 256) * HD;

    const int tid  = threadIdx.x;
    const int wave = tid >> 6;
    const int lane = tid & 63;
    const int l31  = lane & 31;
    const int hl   = lane >> 5;

    const float SC = 0.125f * 1.4426950408889634f;  // 1/sqrt(64) * log2(e)

    // Q B-fragments: qf[qt][kk], lane holds Q[wave*64+qt*32+l31][kk*16+hl*8+i]*SC
    bf16x8 qf[2][4];
#pragma unroll
    for (int qt = 0; qt < 2; ++qt)
#pragma unroll
      for (int kk = 0; kk < 4; ++kk) {
        const float* src = Qb + (size_t)(wave*64 + qt*32 + l31) * HD + kk*16 + hl*8;
        float4 a = *(const float4*)src;
        float4 b = *(const float4*)(src + 4);
        float f[8] = {a.x,a.y,a.z,a.w,b.x,b.y,b.z,b.w};
        bf16x8 v;
#pragma unroll
        for (int i = 0; i < 8; ++i) v[i] = (bf16_t)(f[i] * SC);
        qf[qt][kk] = v;
      }

    f32x16 oacc[2][2];   // [dt][qt]  O^T accumulators
    float lsum[2] = {0.f, 0.f};   // in-lane fp32 P-sum (half the keys; partner via shfl)
#pragma unroll
    for (int i = 0; i < 16; ++i) {
      oacc[0][0][i] = 0.f; oacc[0][1][i] = 0.f;
      oacc[1][0][i] = 0.f; oacc[1][1][i] = 0.f;
    }

    // staging source coords (thread t fills flat LDS bytes t*16 and 4096+t*16
    // of each array; global sources chosen to match the fragment content)
    const int krow = tid & 31;
    const int kcol = ((tid >> 6) & 3) * 16 + ((tid >> 5) & 1) * 8;
    const int vkey = ((tid >> 6) & 3) * 16 + ((tid >> 5) & 1) * 8;
    const int vd   = tid & 31;

    float4 kr0, kr1, kr2, kr3;
    float vra[8], vrb[8];

    auto LOADT = [&](int it) {
      const float* Ksrc = Kb + (size_t)(it * 64) * HD;
      const float* Vsrc = Vb + (size_t)(it * 64) * HD;
      kr0 = *(const float4*)(Ksrc + (size_t)krow * HD + kcol);
      kr1 = *(const float4*)(Ksrc + (size_t)krow * HD + kcol + 4);
      kr2 = *(const float4*)(Ksrc + (size_t)(krow + 32) * HD + kcol);
      kr3 = *(const float4*)(Ksrc + (size_t)(krow + 32) * HD + kcol + 4);
#pragma unroll
      for (int i = 0; i < 8; ++i) {
        vra[i] = Vsrc[(size_t)(vkey + i) * HD + vd];
        vrb[i] = Vsrc[(size_t)(vkey + i) * HD + vd + 32];
      }
    };
    auto STORET = [&](int buf) {
      u16x8_t a;
      a[0]=f2b(kr0.x); a[1]=f2b(kr0.y); a[2]=f2b(kr0.z); a[3]=f2b(kr0.w);
      a[4]=f2b(kr1.x); a[5]=f2b(kr1.y); a[6]=f2b(kr1.z); a[7]=f2b(kr1.w);
      *(u16x8_t*)&Kf[buf][tid*8] = a;
      a[0]=f2b(kr2.x); a[1]=f2b(kr2.y); a[2]=f2b(kr2.z); a[3]=f2b(kr2.w);
      a[4]=f2b(kr3.x); a[5]=f2b(kr3.y); a[6]=f2b(kr3.z); a[7]=f2b(kr3.w);
      *(u16x8_t*)&Kf[buf][2048 + tid*8] = a;
      u16x8_t b;
#pragma unroll
      for (int i = 0; i < 8; ++i) b[i] = f2b(vra[i]);
      *(u16x8_t*)&Vff[buf][tid*8] = b;
#pragma unroll
      for (int i = 0; i < 8; ++i) b[i] = f2b(vrb[i]);
      *(u16x8_t*)&Vff[buf][2048 + tid*8] = b;
    };

    const int niter = Slen >> 6;
    LOADT(0);
    STORET(0);
    __syncthreads();

    for (int it = 0; it < niter; ++it) {
      const int cur = it & 1;
      const bool more = (it + 1 < niter);
      if (more) LOADT(it + 1);   // T14: in flight across the whole iteration

      // K fragments (shared by both q-tiles)
      bf16x8 kf[8];
#pragma unroll
      for (int c2 = 0; c2 < 8; ++c2)
        kf[c2] = asbf(*(const u16x8_t*)&Kf[cur][c2*512 + lane*8]);

      u32x4_t pb[2][4];   // [qt][kk4]  P^T B-fragments
#pragma unroll
      for (int qt = 0; qt < 2; ++qt) {
        f32x16 s0, s1;
#pragma unroll
        for (int i = 0; i < 16; ++i) { s0[i] = 0.f; s1[i] = 0.f; }
        __builtin_amdgcn_s_setprio(1);
#pragma unroll
        for (int kk = 0; kk < 4; ++kk) {
          s0 = __builtin_amdgcn_mfma_f32_32x32x16_bf16(kf[kk],     qf[qt][kk], s0, 0, 0, 0);
          s1 = __builtin_amdgcn_mfma_f32_32x32x16_bf16(kf[4 + kk], qf[qt][kk], s1, 0, 0, 0);
        }
        __builtin_amdgcn_s_setprio(0);
        // no-max softmax: P = exp2(s) (branch-free); fused l-sum; pack;
        // redistribute C-layout -> B-layout. permlane32_swap(first, second)
        // exchanges first.lanes[32:63] <-> second.lanes[0:31], so the LOWER
        // word is the FIRST operand: swap(w0,w2), swap(w1,w3).
        float ls = 0.f;
#pragma unroll
        for (int kt = 0; kt < 2; ++kt) {
          const f32x16& s = kt ? s1 : s0;
#pragma unroll
          for (int m = 0; m < 2; ++m) {
            float e0 = __builtin_amdgcn_exp2f(s[8*m+0]), e1 = __builtin_amdgcn_exp2f(s[8*m+1]);
            float e2 = __builtin_amdgcn_exp2f(s[8*m+2]), e3 = __builtin_amdgcn_exp2f(s[8*m+3]);
            float e4 = __builtin_amdgcn_exp2f(s[8*m+4]), e5 = __builtin_amdgcn_exp2f(s[8*m+5]);
            float e6 = __builtin_amdgcn_exp2f(s[8*m+6]), e7 = __builtin_amdgcn_exp2f(s[8*m+7]);
            ls += ((e0+e1)+(e2+e3)) + ((e4+e5)+(e6+e7));
            unsigned int w0 = pk2(e0, e1);
            unsigned int w1 = pk2(e2, e3);
            unsigned int w2 = pk2(e4, e5);
            unsigned int w3 = pk2(e6, e7);
            asm("v_permlane32_swap_b32 %0, %1" : "+v"(w0), "+v"(w2));
            asm("v_permlane32_swap_b32 %0, %1" : "+v"(w1), "+v"(w3));
            pb[qt][2*kt + m] = (u32x4_t){w0, w1, w2, w3};
          }
        }
        lsum[qt] += ls;
      }

      // PV: O^T += V^T . P^T (V frags just-in-time)
      __builtin_amdgcn_s_setprio(1);
#pragma unroll
      for (int kk4 = 0; kk4 < 4; ++kk4) {
        bf16x8 v0 = asbf(*(const u16x8_t*)&Vff[cur][kk4*512 + lane*8]);
        bf16x8 v1 = asbf(*(const u16x8_t*)&Vff[cur][(4 + kk4)*512 + lane*8]);
        bf16x8 p0 = asbf4(pb[0][kk4]);
        bf16x8 p1 = asbf4(pb[1][kk4]);
        oacc[0][0] = __builtin_amdgcn_mfma_f32_32x32x16_bf16(v0, p0, oacc[0][0], 0, 0, 0);
        oacc[0][1] = __builtin_amdgcn_mfma_f32_32x32x16_bf16(v0, p1, oacc[0][1], 0, 0, 0);
        oacc[1][0] = __builtin_amdgcn_mfma_f32_32x32x16_bf16(v1, p0, oacc[1][0], 0, 0, 0);
        oacc[1][1] = __builtin_amdgcn_mfma_f32_32x32x16_bf16(v1, p1, oacc[1][1], 0, 0, 0);
      }
      __builtin_amdgcn_s_setprio(0);

      if (more) {
        STORET(cur ^ 1);
        __syncthreads();
      }
    }

    // epilogue: l = own half-sum + partner half (shfl_xor 32); O = oacc / l
#pragma unroll
    for (int qt = 0; qt < 2; ++qt) {
      float lt = lsum[qt] + __shfl_xor(lsum[qt], 32);
      float inv = 1.0f / lt;
      float* dst = Ob + (size_t)(wave*64 + qt*32 + l31) * HD + hl*4;
#pragma unroll
      for (int dt = 0; dt < 2; ++dt)
#pragma unroll
        for (int b = 0; b < 4; ++b) {
          float4 o4;
          o4.x = oacc[dt][qt][4*b+0] * inv;
          o4.y = oacc[dt][qt][4*b+1] * inv;
          o4.z = oacc[dt][qt][4*b+2] * inv;
          o4.w = oacc[dt][qt][4*b+3] * inv;
          *(float4*)(dst + dt*32 + b*8) = o4;
        }
    }
}

extern "C" void kernel_launch(void* const* d_in, const int* in_sizes, int n_in,
                              void* d_out, int out_size, void* d_ws, size_t ws_size,
                              hipStream_t stream) {
    (void)in_sizes; (void)n_in; (void)out_size; (void)d_ws; (void)ws_size;
    const float* Q = (const float*)d_in[0];
    const float* K = (const float*)d_in[1];
    const float* V = (const float*)d_in[2];
    float* O = (float*)d_out;
    flash_attn_kernel<<<dim3(1536), dim3(256), 0, stream>>>(Q, K, V, O);
}

// Round 15
// 195.795 us; speedup vs baseline: 2.8888x; 2.8888x over previous
//
#include <hip/hip_runtime.h>

typedef __bf16 bf16_t;
typedef bf16_t bf16x8 __attribute__((ext_vector_type(8)));
typedef float f32x16 __attribute__((ext_vector_type(16)));
typedef unsigned short u16x8_t __attribute__((ext_vector_type(8)));
typedef unsigned int u32x4_t __attribute__((ext_vector_type(4)));

#define HD 64
#define TOTTOK 49152

static __device__ __forceinline__ unsigned short f2b(float f) {
    bf16_t h = (bf16_t)f;
    return __builtin_bit_cast(unsigned short, h);
}
static __device__ __forceinline__ bf16x8 asbf(u16x8_t u) { return __builtin_bit_cast(bf16x8, u); }
static __device__ __forceinline__ bf16x8 asbf4(u32x4_t u) { return __builtin_bit_cast(bf16x8, u); }
static __device__ __forceinline__ unsigned int pk2(float lo, float hi) {
    return (unsigned int)f2b(lo) | ((unsigned int)f2b(hi) << 16);
}

// ===== The FROZEN R9 body (verbatim phases; textual macro, self-contained:
// reads K/V fragments from the given LDS bases, accumulates oacc/lacc). =====
#define BODY(KBASE, VBASE)                                                             \
  do {                                                                                 \
    bf16x8 kf[8];                                                                      \
    _Pragma("unroll")                                                                  \
    for (int c2 = 0; c2 < 8; ++c2)                                                     \
      kf[c2] = asbf(*(const u16x8_t*)((KBASE) + c2*512 + lane*8));                     \
    u32x4_t pb[2][4];                                                                  \
    _Pragma("unroll")                                                                  \
    for (int qt = 0; qt < 2; ++qt) {                                                   \
      f32x16 s0, s1;                                                                   \
      _Pragma("unroll")                                                                \
      for (int i = 0; i < 16; ++i) { s0[i] = 0.f; s1[i] = 0.f; }                       \
      __builtin_amdgcn_s_setprio(1);                                                   \
      _Pragma("unroll")                                                                \
      for (int kk = 0; kk < 4; ++kk) {                                                 \
        s0 = __builtin_amdgcn_mfma_f32_32x32x16_bf16(kf[kk],   qf[qt][kk], s0, 0, 0, 0); \
        s1 = __builtin_amdgcn_mfma_f32_32x32x16_bf16(kf[4+kk], qf[qt][kk], s1, 0, 0, 0); \
      }                                                                                \
      __builtin_amdgcn_s_setprio(0);                                                   \
      _Pragma("unroll")                                                                \
      for (int kt = 0; kt < 2; ++kt) {                                                 \
        const f32x16& s = kt ? s1 : s0;                                                \
        _Pragma("unroll")                                                              \
        for (int m = 0; m < 2; ++m) {                                                  \
          unsigned int w0 = pk2(__builtin_amdgcn_exp2f(s[8*m+0]), __builtin_amdgcn_exp2f(s[8*m+1])); \
          unsigned int w1 = pk2(__builtin_amdgcn_exp2f(s[8*m+2]), __builtin_amdgcn_exp2f(s[8*m+3])); \
          unsigned int w2 = pk2(__builtin_amdgcn_exp2f(s[8*m+4]), __builtin_amdgcn_exp2f(s[8*m+5])); \
          unsigned int w3 = pk2(__builtin_amdgcn_exp2f(s[8*m+6]), __builtin_amdgcn_exp2f(s[8*m+7])); \
          asm("v_permlane32_swap_b32 %0, %1" : "+v"(w0), "+v"(w2));                    \
          asm("v_permlane32_swap_b32 %0, %1" : "+v"(w1), "+v"(w3));                    \
          pb[qt][2*kt + m] = (u32x4_t){w0, w1, w2, w3};                                \
        }                                                                              \
      }                                                                                \
    }                                                                                  \
    __builtin_amdgcn_s_setprio(1);                                                     \
    _Pragma("unroll")                                                                  \
    for (int kk4 = 0; kk4 < 4; ++kk4) {                                                \
      bf16x8 v0 = asbf(*(const u16x8_t*)((VBASE) + kk4*512 + lane*8));                 \
      bf16x8 v1 = asbf(*(const u16x8_t*)((VBASE) + (4+kk4)*512 + lane*8));             \
      bf16x8 p0 = asbf4(pb[0][kk4]);                                                   \
      bf16x8 p1 = asbf4(pb[1][kk4]);                                                   \
      lacc[0] = __builtin_amdgcn_mfma_f32_32x32x16_bf16(ones, p0, lacc[0], 0, 0, 0);   \
      lacc[1] = __builtin_amdgcn_mfma_f32_32x32x16_bf16(ones, p1, lacc[1], 0, 0, 0);   \
      oacc[0][0] = __builtin_amdgcn_mfma_f32_32x32x16_bf16(v0, p0, oacc[0][0], 0, 0, 0); \
      oacc[0][1] = __builtin_amdgcn_mfma_f32_32x32x16_bf16(v0, p1, oacc[0][1], 0, 0, 0); \
      oacc[1][0] = __builtin_amdgcn_mfma_f32_32x32x16_bf16(v1, p0, oacc[1][0], 0, 0, 0); \
      oacc[1][1] = __builtin_amdgcn_mfma_f32_32x32x16_bf16(v1, p1, oacc[1][1], 0, 0, 0); \
    }                                                                                  \
    __builtin_amdgcn_s_setprio(0);                                                     \
  } while (0)

__global__ __launch_bounds__(256, 2)
void flash_attn_kernel(const float* __restrict__ Q, const float* __restrict__ K,
                       const float* __restrict__ V, float* __restrict__ O)
{
    // KVB=128 epochs: two 64-key sub-tiles per barrier-epoch, each staged and
    // consumed exactly like the R9 champion (fragment-major LDS, 8 chunks x
    // 512 shorts per sub-tile, lane-linear ds_read_b128, 0 conflicts).
    // [buf][sub][...]; 64KB LDS total -> 2 blocks/CU.
    __shared__ unsigned short Kf[2][2][4096];
    __shared__ unsigned short Vff[2][2][4096];

    const int bid = blockIdx.x;
    int Slen, bl2, off, qtl2, base;
    if (bid < 512)       { Slen = 2048; bl2 = 3; off = 32768; qtl2 = 3; base = 0;    }
    else if (bid < 1024) { Slen = 1024; bl2 = 4; off = 16384; qtl2 = 2; base = 512;  }
    else                 { Slen = 512;  bl2 = 5; off = 0;     qtl2 = 1; base = 1024; }
    const int l    = bid - base;
    const int xcd  = l & 7;
    const int slot = l >> 3;
    const int p    = xcd + ((slot >> qtl2) << 3);
    const int qblk = slot & ((1 << qtl2) - 1);
    const int hh   = p >> bl2;
    const int sj   = p & ((1 << bl2) - 1);

    const size_t seqbase = ((size_t)hh * TOTTOK + (size_t)off + (size_t)sj * Slen) * HD;
    const float* Qb = Q + seqbase + (size_t)(qblk * 256) * HD;
    const float* Kb = K + seqbase;
    const float* Vb = V + seqbase;
    float*       Ob = O + seqbase + (size_t)(qblk * 256) * HD;

    const int tid  = threadIdx.x;
    const int wave = tid >> 6;
    const int lane = tid & 63;
    const int l31  = lane & 31;
    const int hl   = lane >> 5;

    const float SC = 0.125f * 1.4426950408889634f;  // 1/sqrt(64) * log2(e)

    // Q B-fragments (verbatim R9)
    bf16x8 qf[2][4];
#pragma unroll
    for (int qt = 0; qt < 2; ++qt)
#pragma unroll
      for (int kk = 0; kk < 4; ++kk) {
        const float* src = Qb + (size_t)(wave*64 + qt*32 + l31) * HD + kk*16 + hl*8;
        float4 a = *(const float4*)src;
        float4 b = *(const float4*)(src + 4);
        float f[8] = {a.x,a.y,a.z,a.w,b.x,b.y,b.z,b.w};
        bf16x8 v;
#pragma unroll
        for (int i = 0; i < 8; ++i) v[i] = (bf16_t)(f[i] * SC);
        qf[qt][kk] = v;
      }

    f32x16 oacc[2][2];   // [dt][qt]
    f32x16 lacc[2];      // ones-MFMA l (R13 lesson: must stay on MFMA/AGPR path)
#pragma unroll
    for (int i = 0; i < 16; ++i) {
      oacc[0][0][i] = 0.f; oacc[0][1][i] = 0.f;
      oacc[1][0][i] = 0.f; oacc[1][1][i] = 0.f;
      lacc[0][i] = 0.f;    lacc[1][i] = 0.f;
    }

    u16x8_t onesu;
#pragma unroll
    for (int i = 0; i < 8; ++i) onesu[i] = 0x3F80;  // bf16 1.0
    const bf16x8 ones = asbf(onesu);

    // staging coords (verbatim R9; LOADT keeps K+V paired — the proven form)
    const int krow = tid & 31;
    const int kcol = ((tid >> 6) & 3) * 16 + ((tid >> 5) & 1) * 8;
    const int vkey = ((tid >> 6) & 3) * 16 + ((tid >> 5) & 1) * 8;
    const int vd   = tid & 31;

    float4 kr0, kr1, kr2, kr3;
    float vra[8], vrb[8];

    auto LOADT = [&](int keybase) {
      const float* Ksrc = Kb + (size_t)keybase * HD;
      const float* Vsrc = Vb + (size_t)keybase * HD;
      kr0 = *(const float4*)(Ksrc + (size_t)krow * HD + kcol);
      kr1 = *(const float4*)(Ksrc + (size_t)krow * HD + kcol + 4);
      kr2 = *(const float4*)(Ksrc + (size_t)(krow + 32) * HD + kcol);
      kr3 = *(const float4*)(Ksrc + (size_t)(krow + 32) * HD + kcol + 4);
#pragma unroll
      for (int i = 0; i < 8; ++i) {
        vra[i] = Vsrc[(size_t)(vkey + i) * HD + vd];
        vrb[i] = Vsrc[(size_t)(vkey + i) * HD + vd + 32];
      }
    };
    auto STORET = [&](unsigned short* kdst, unsigned short* vdst) {
      u16x8_t a;
      a[0]=f2b(kr0.x); a[1]=f2b(kr0.y); a[2]=f2b(kr0.z); a[3]=f2b(kr0.w);
      a[4]=f2b(kr1.x); a[5]=f2b(kr1.y); a[6]=f2b(kr1.z); a[7]=f2b(kr1.w);
      *(u16x8_t*)(kdst + tid*8) = a;
      a[0]=f2b(kr2.x); a[1]=f2b(kr2.y); a[2]=f2b(kr2.z); a[3]=f2b(kr2.w);
      a[4]=f2b(kr3.x); a[5]=f2b(kr3.y); a[6]=f2b(kr3.z); a[7]=f2b(kr3.w);
      *(u16x8_t*)(kdst + 2048 + tid*8) = a;
      u16x8_t b;
#pragma unroll
      for (int i = 0; i < 8; ++i) b[i] = f2b(vra[i]);
      *(u16x8_t*)(vdst + tid*8) = b;
#pragma unroll
      for (int i = 0; i < 8; ++i) b[i] = f2b(vrb[i]);
      *(u16x8_t*)(vdst + 2048 + tid*8) = b;
    };

    const int nep = Slen >> 7;   // 4, 8, or 16 epochs of 128 keys

    // prologue: stage epoch 0 (both sub-tiles)
    LOADT(0);
    STORET(&Kf[0][0][0], &Vff[0][0][0]);
    LOADT(64);
    STORET(&Kf[0][1][0], &Vff[0][1][0]);
    __syncthreads();

    for (int ep = 0; ep < nep; ++ep) {
      const int cur = ep & 1;
      const bool more = (ep + 1 < nep);
      if (more) LOADT((ep + 1) * 128);                       // next epoch sub0
      BODY(&Kf[cur][0][0], &Vff[cur][0][0]);                 // keys ep*128 .. +63
      if (more) {
        STORET(&Kf[cur ^ 1][0][0], &Vff[cur ^ 1][0][0]);     // safe: ep-1 readers done at ep-1 barrier
        LOADT((ep + 1) * 128 + 64);                          // next epoch sub1
      }
      BODY(&Kf[cur][1][0], &Vff[cur][1][0]);                 // keys ep*128+64 .. +127
      if (more) {
        STORET(&Kf[cur ^ 1][1][0], &Vff[cur ^ 1][1][0]);
        __syncthreads();                                     // ONE barrier per 128 keys
      }
    }

    // epilogue (verbatim R9): O[q][d] = oacc / l
#pragma unroll
    for (int qt = 0; qt < 2; ++qt) {
      float inv = 1.0f / lacc[qt][0];
      float* dst = Ob + (size_t)(wave*64 + qt*32 + l31) * HD + hl*4;
#pragma unroll
      for (int dt = 0; dt < 2; ++dt)
#pragma unroll
        for (int b = 0; b < 4; ++b) {
          float4 o4;
          o4.x = oacc[dt][qt][4*b+0] * inv;
          o4.y = oacc[dt][qt][4*b+1] * inv;
          o4.z = oacc[dt][qt][4*b+2] * inv;
          o4.w = oacc[dt][qt][4*b+3] * inv;
          *(float4*)(dst + dt*32 + b*8) = o4;
        }
    }
}

extern "C" void kernel_launch(void* const* d_in, const int* in_sizes, int n_in,
                              void* d_out, int out_size, void* d_ws, size_t ws_size,
                              hipStream_t stream) {
    (void)in_sizes; (void)n_in; (void)out_size; (void)d_ws; (void)ws_size;
    const float* Q = (const float*)d_in[0];
    const float* K = (const float*)d_in[1];
    const float* V = (const float*)d_in[2];
    float* O = (float*)d_out;
    flash_attn_kernel<<<dim3(1536), dim3(256), 0, stream>>>(Q, K, V, O);
}

// Round 16
// 188.991 us; speedup vs baseline: 2.9928x; 1.0360x over previous
//
#include <hip/hip_runtime.h>

typedef __bf16 bf16_t;
typedef bf16_t bf16x8 __attribute__((ext_vector_type(8)));
typedef float f32x16 __attribute__((ext_vector_type(16)));
typedef unsigned short u16x8_t __attribute__((ext_vector_type(8)));
typedef unsigned int u32x4_t __attribute__((ext_vector_type(4)));

#define HD 64
#define TOTTOK 49152

static __device__ __forceinline__ unsigned short f2b(float f) {
    bf16_t h = (bf16_t)f;
    return __builtin_bit_cast(unsigned short, h);
}
static __device__ __forceinline__ bf16x8 asbf(u16x8_t u) { return __builtin_bit_cast(bf16x8, u); }
static __device__ __forceinline__ bf16x8 asbf4(u32x4_t u) { return __builtin_bit_cast(bf16x8, u); }
static __device__ __forceinline__ unsigned int pk2(float lo, float hi) {
    return (unsigned int)f2b(lo) | ((unsigned int)f2b(hi) << 16);
}

// ===== The FROZEN R9 body, MINUS s_setprio (R16 single-variable ablation:
// setprio(1) bursts serialize the 2 co-resident waves' phases on a SIMD). =====
#define BODY(KBASE, VBASE)                                                             \
  do {                                                                                 \
    bf16x8 kf[8];                                                                      \
    _Pragma("unroll")                                                                  \
    for (int c2 = 0; c2 < 8; ++c2)                                                     \
      kf[c2] = asbf(*(const u16x8_t*)((KBASE) + c2*512 + lane*8));                     \
    u32x4_t pb[2][4];                                                                  \
    _Pragma("unroll")                                                                  \
    for (int qt = 0; qt < 2; ++qt) {                                                   \
      f32x16 s0, s1;                                                                   \
      _Pragma("unroll")                                                                \
      for (int i = 0; i < 16; ++i) { s0[i] = 0.f; s1[i] = 0.f; }                       \
      _Pragma("unroll")                                                                \
      for (int kk = 0; kk < 4; ++kk) {                                                 \
        s0 = __builtin_amdgcn_mfma_f32_32x32x16_bf16(kf[kk],   qf[qt][kk], s0, 0, 0, 0); \
        s1 = __builtin_amdgcn_mfma_f32_32x32x16_bf16(kf[4+kk], qf[qt][kk], s1, 0, 0, 0); \
      }                                                                                \
      _Pragma("unroll")                                                                \
      for (int kt = 0; kt < 2; ++kt) {                                                 \
        const f32x16& s = kt ? s1 : s0;                                                \
        _Pragma("unroll")                                                              \
        for (int m = 0; m < 2; ++m) {                                                  \
          unsigned int w0 = pk2(__builtin_amdgcn_exp2f(s[8*m+0]), __builtin_amdgcn_exp2f(s[8*m+1])); \
          unsigned int w1 = pk2(__builtin_amdgcn_exp2f(s[8*m+2]), __builtin_amdgcn_exp2f(s[8*m+3])); \
          unsigned int w2 = pk2(__builtin_amdgcn_exp2f(s[8*m+4]), __builtin_amdgcn_exp2f(s[8*m+5])); \
          unsigned int w3 = pk2(__builtin_amdgcn_exp2f(s[8*m+6]), __builtin_amdgcn_exp2f(s[8*m+7])); \
          asm("v_permlane32_swap_b32 %0, %1" : "+v"(w0), "+v"(w2));                    \
          asm("v_permlane32_swap_b32 %0, %1" : "+v"(w1), "+v"(w3));                    \
          pb[qt][2*kt + m] = (u32x4_t){w0, w1, w2, w3};                                \
        }                                                                              \
      }                                                                                \
    }                                                                                  \
    _Pragma("unroll")                                                                  \
    for (int kk4 = 0; kk4 < 4; ++kk4) {                                                \
      bf16x8 v0 = asbf(*(const u16x8_t*)((VBASE) + kk4*512 + lane*8));                 \
      bf16x8 v1 = asbf(*(const u16x8_t*)((VBASE) + (4+kk4)*512 + lane*8));             \
      bf16x8 p0 = asbf4(pb[0][kk4]);                                                   \
      bf16x8 p1 = asbf4(pb[1][kk4]);                                                   \
      lacc[0] = __builtin_amdgcn_mfma_f32_32x32x16_bf16(ones, p0, lacc[0], 0, 0, 0);   \
      lacc[1] = __builtin_amdgcn_mfma_f32_32x32x16_bf16(ones, p1, lacc[1], 0, 0, 0);   \
      oacc[0][0] = __builtin_amdgcn_mfma_f32_32x32x16_bf16(v0, p0, oacc[0][0], 0, 0, 0); \
      oacc[0][1] = __builtin_amdgcn_mfma_f32_32x32x16_bf16(v0, p1, oacc[0][1], 0, 0, 0); \
      oacc[1][0] = __builtin_amdgcn_mfma_f32_32x32x16_bf16(v1, p0, oacc[1][0], 0, 0, 0); \
      oacc[1][1] = __builtin_amdgcn_mfma_f32_32x32x16_bf16(v1, p1, oacc[1][1], 0, 0, 0); \
    }                                                                                  \
  } while (0)

__global__ __launch_bounds__(256, 2)
void flash_attn_kernel(const float* __restrict__ Q, const float* __restrict__ K,
                       const float* __restrict__ V, float* __restrict__ O)
{
    // KVB=128 epochs: two 64-key sub-tiles per barrier-epoch (R15 structure).
    __shared__ unsigned short Kf[2][2][4096];
    __shared__ unsigned short Vff[2][2][4096];

    const int bid = blockIdx.x;
    int Slen, bl2, off, qtl2, base;
    if (bid < 512)       { Slen = 2048; bl2 = 3; off = 32768; qtl2 = 3; base = 0;    }
    else if (bid < 1024) { Slen = 1024; bl2 = 4; off = 16384; qtl2 = 2; base = 512;  }
    else                 { Slen = 512;  bl2 = 5; off = 0;     qtl2 = 1; base = 1024; }
    const int l    = bid - base;
    const int xcd  = l & 7;
    const int slot = l >> 3;
    const int p    = xcd + ((slot >> qtl2) << 3);
    const int qblk = slot & ((1 << qtl2) - 1);
    const int hh   = p >> bl2;
    const int sj   = p & ((1 << bl2) - 1);

    const size_t seqbase = ((size_t)hh * TOTTOK + (size_t)off + (size_t)sj * Slen) * HD;
    const float* Qb = Q + seqbase + (size_t)(qblk * 256) * HD;
    const float* Kb = K + seqbase;
    const float* Vb = V + seqbase;
    float*       Ob = O + seqbase + (size_t)(qblk * 256) * HD;

    const int tid  = threadIdx.x;
    const int wave = tid >> 6;
    const int lane = tid & 63;
    const int l31  = lane & 31;
    const int hl   = lane >> 5;

    const float SC = 0.125f * 1.4426950408889634f;  // 1/sqrt(64) * log2(e)

    // Q B-fragments (verbatim R9)
    bf16x8 qf[2][4];
#pragma unroll
    for (int qt = 0; qt < 2; ++qt)
#pragma unroll
      for (int kk = 0; kk < 4; ++kk) {
        const float* src = Qb + (size_t)(wave*64 + qt*32 + l31) * HD + kk*16 + hl*8;
        float4 a = *(const float4*)src;
        float4 b = *(const float4*)(src + 4);
        float f[8] = {a.x,a.y,a.z,a.w,b.x,b.y,b.z,b.w};
        bf16x8 v;
#pragma unroll
        for (int i = 0; i < 8; ++i) v[i] = (bf16_t)(f[i] * SC);
        qf[qt][kk] = v;
      }

    f32x16 oacc[2][2];   // [dt][qt]
    f32x16 lacc[2];      // ones-MFMA l (R13: must stay on MFMA/AGPR path)
#pragma unroll
    for (int i = 0; i < 16; ++i) {
      oacc[0][0][i] = 0.f; oacc[0][1][i] = 0.f;
      oacc[1][0][i] = 0.f; oacc[1][1][i] = 0.f;
      lacc[0][i] = 0.f;    lacc[1][i] = 0.f;
    }

    u16x8_t onesu;
#pragma unroll
    for (int i = 0; i < 8; ++i) onesu[i] = 0x3F80;  // bf16 1.0
    const bf16x8 ones = asbf(onesu);

    // staging coords (verbatim R9; LOADT keeps K+V paired — the proven form)
    const int krow = tid & 31;
    const int kcol = ((tid >> 6) & 3) * 16 + ((tid >> 5) & 1) * 8;
    const int vkey = ((tid >> 6) & 3) * 16 + ((tid >> 5) & 1) * 8;
    const int vd   = tid & 31;

    float4 kr0, kr1, kr2, kr3;
    float vra[8], vrb[8];

    auto LOADT = [&](int keybase) {
      const float* Ksrc = Kb + (size_t)keybase * HD;
      const float* Vsrc = Vb + (size_t)keybase * HD;
      kr0 = *(const float4*)(Ksrc + (size_t)krow * HD + kcol);
      kr1 = *(const float4*)(Ksrc + (size_t)krow * HD + kcol + 4);
      kr2 = *(const float4*)(Ksrc + (size_t)(krow + 32) * HD + kcol);
      kr3 = *(const float4*)(Ksrc + (size_t)(krow + 32) * HD + kcol + 4);
#pragma unroll
      for (int i = 0; i < 8; ++i) {
        vra[i] = Vsrc[(size_t)(vkey + i) * HD + vd];
        vrb[i] = Vsrc[(size_t)(vkey + i) * HD + vd + 32];
      }
    };
    auto STORET = [&](unsigned short* kdst, unsigned short* vdst) {
      u16x8_t a;
      a[0]=f2b(kr0.x); a[1]=f2b(kr0.y); a[2]=f2b(kr0.z); a[3]=f2b(kr0.w);
      a[4]=f2b(kr1.x); a[5]=f2b(kr1.y); a[6]=f2b(kr1.z); a[7]=f2b(kr1.w);
      *(u16x8_t*)(kdst + tid*8) = a;
      a[0]=f2b(kr2.x); a[1]=f2b(kr2.y); a[2]=f2b(kr2.z); a[3]=f2b(kr2.w);
      a[4]=f2b(kr3.x); a[5]=f2b(kr3.y); a[6]=f2b(kr3.z); a[7]=f2b(kr3.w);
      *(u16x8_t*)(kdst + 2048 + tid*8) = a;
      u16x8_t b;
#pragma unroll
      for (int i = 0; i < 8; ++i) b[i] = f2b(vra[i]);
      *(u16x8_t*)(vdst + tid*8) = b;
#pragma unroll
      for (int i = 0; i < 8; ++i) b[i] = f2b(vrb[i]);
      *(u16x8_t*)(vdst + 2048 + tid*8) = b;
    };

    const int nep = Slen >> 7;   // 4, 8, or 16 epochs of 128 keys

    // prologue: stage epoch 0 (both sub-tiles)
    LOADT(0);
    STORET(&Kf[0][0][0], &Vff[0][0][0]);
    LOADT(64);
    STORET(&Kf[0][1][0], &Vff[0][1][0]);
    __syncthreads();

    for (int ep = 0; ep < nep; ++ep) {
      const int cur = ep & 1;
      const bool more = (ep + 1 < nep);
      if (more) LOADT((ep + 1) * 128);                       // next epoch sub0
      BODY(&Kf[cur][0][0], &Vff[cur][0][0]);                 // keys ep*128 .. +63
      if (more) {
        STORET(&Kf[cur ^ 1][0][0], &Vff[cur ^ 1][0][0]);     // ep-1 readers done at ep-1 barrier
        LOADT((ep + 1) * 128 + 64);                          // next epoch sub1
      }
      BODY(&Kf[cur][1][0], &Vff[cur][1][0]);                 // keys ep*128+64 .. +127
      if (more) {
        STORET(&Kf[cur ^ 1][1][0], &Vff[cur ^ 1][1][0]);
        __syncthreads();                                     // ONE barrier per 128 keys
      }
    }

    // epilogue (verbatim R9): O[q][d] = oacc / l
#pragma unroll
    for (int qt = 0; qt < 2; ++qt) {
      float inv = 1.0f / lacc[qt][0];
      float* dst = Ob + (size_t)(wave*64 + qt*32 + l31) * HD + hl*4;
#pragma unroll
      for (int dt = 0; dt < 2; ++dt)
#pragma unroll
        for (int b = 0; b < 4; ++b) {
          float4 o4;
          o4.x = oacc[dt][qt][4*b+0] * inv;
          o4.y = oacc[dt][qt][4*b+1] * inv;
          o4.z = oacc[dt][qt][4*b+2] * inv;
          o4.w = oacc[dt][qt][4*b+3] * inv;
          *(float4*)(dst + dt*32 + b*8) = o4;
        }
    }
}

extern "C" void kernel_launch(void* const* d_in, const int* in_sizes, int n_in,
                              void* d_out, int out_size, void* d_ws, size_t ws_size,
                              hipStream_t stream) {
    (void)in_sizes; (void)n_in; (void)out_size; (void)d_ws; (void)ws_size;
    const float* Q = (const float*)d_in[0];
    const float* K = (const float*)d_in[1];
    const float* V = (const float*)d_in[2];
    float* O = (float*)d_out;
    flash_attn_kernel<<<dim3(1536), dim3(256), 0, stream>>>(Q, K, V, O);
}